// Round 6
// baseline (311.052 us; speedup 1.0000x reference)
//
#include <hip/hip_runtime.h>
#include <stdint.h>

typedef unsigned short u16;
typedef unsigned int u32;

typedef __bf16 bf8 __attribute__((ext_vector_type(8)));
typedef bf8 bf8a __attribute__((may_alias));
typedef float f32x4 __attribute__((ext_vector_type(4)));
typedef uint2 uint2a __attribute__((may_alias));
typedef ushort4 ushort4a __attribute__((may_alias));
typedef float4 float4a __attribute__((may_alias));

#define MFMA_BF16(a, b, c) __builtin_amdgcn_mfma_f32_16x16x32_bf16((a), (b), (c), 0, 0, 0)

__device__ __forceinline__ u16 f2b(float x) {
  u32 u = __float_as_uint(x);
  return (u16)((u + 0x7fffu + ((u >> 16) & 1u)) >> 16);  // RNE
}
__device__ __forceinline__ u32 pack2(float a, float b) {  // two f32 -> packed bf16x2 (sign-preserving)
  u32 ua = __float_as_uint(a), ub = __float_as_uint(b);
  return ((ua + 0x8000u) >> 16) | ((ub + 0x8000u) & 0xffff0000u);
}
__device__ __forceinline__ void async16(const u16* g, void* l) {
  __builtin_amdgcn_global_load_lds((const __attribute__((address_space(1))) u32*)g,
                                   (__attribute__((address_space(3))) u32*)l, 16, 0, 0);
}

// ---------------------------------------------------------------------------
// src convert: fp32 [4096][1024] -> bf16 same layout. 1 float4 per thread.
// ---------------------------------------------------------------------------
__global__ __launch_bounds__(256) void convert_src(const float* __restrict__ src,
                                                   u16* __restrict__ dst) {
  const int i = blockIdx.x * 256 + threadIdx.x;  // float4 index
  float4 v = *(const float4a*)(src + i * 4);
  ushort4 o;
  o.x = f2b(v.x); o.y = f2b(v.y); o.z = f2b(v.z); o.w = f2b(v.w);
  *(ushort4a*)(dst + i * 4) = o;
}

// ---------------------------------------------------------------------------
// EB precompute: fp32 [2048][2048] -> bf16 sign(b)*exp(b), 16x16-tiled layout:
// E2[(s>>4)*128 + (t>>4)][ (s&15)*16 + (t&15) ]  (256 elem = 512 B per tile)
// ---------------------------------------------------------------------------
__global__ __launch_bounds__(256) void prep_eb(const float* __restrict__ EB,
                                               u16* __restrict__ E2) {
  const int gid = blockIdx.x * 256 + threadIdx.x;
  const int s = gid >> 9;            // 512 float4 per row
  const int t = (gid & 511) * 4;
  const float4 v = *(const float4a*)(EB + s * 2048 + t);
  const float c2 = 1.44269504088896340736f;  // log2(e)
  ushort4 o;
  o.x = f2b(__builtin_amdgcn_exp2f(v.x * c2)) | (u16)((__float_as_uint(v.x) >> 16) & 0x8000u);
  o.y = f2b(__builtin_amdgcn_exp2f(v.y * c2)) | (u16)((__float_as_uint(v.y) >> 16) & 0x8000u);
  o.z = f2b(__builtin_amdgcn_exp2f(v.z * c2)) | (u16)((__float_as_uint(v.z) >> 16) & 0x8000u);
  o.w = f2b(__builtin_amdgcn_exp2f(v.w * c2)) | (u16)((__float_as_uint(v.w) >> 16) & 0x8000u);
  const int ti = ((s >> 4) * 128 + (t >> 4)) * 256 + (s & 15) * 16 + (t & 15);
  *(ushort4a*)(E2 + ti) = o;
}

// ---------------------------------------------------------------------------
// Weight transpose+convert: w fp32 [K=1024][N=1024] -> wT bf16 [N][K]
// ---------------------------------------------------------------------------
__global__ __launch_bounds__(256) void transpose4(
    const float* __restrict__ w0, const float* __restrict__ w1,
    const float* __restrict__ w2, const float* __restrict__ w3,
    u16* __restrict__ t0, u16* __restrict__ t1, u16* __restrict__ t2, u16* __restrict__ t3) {
  const int z = blockIdx.z;
  const float* W = z == 0 ? w0 : z == 1 ? w1 : z == 2 ? w2 : w3;
  u16* T = z == 0 ? t0 : z == 1 ? t1 : z == 2 ? t2 : t3;
  __shared__ __align__(8) u16 tile[64][68];
  const int tid = threadIdx.x;
  const int ty = tid >> 4, tx = tid & 15;
  const int kb = blockIdx.y * 64, nb = blockIdx.x * 64;
#pragma unroll
  for (int i = 0; i < 4; ++i) {
    int lk = ty + i * 16;
    float4 v = *(const float4a*)(W + (kb + lk) * 1024 + nb + tx * 4);
    ushort4 h;
    h.x = f2b(v.x); h.y = f2b(v.y); h.z = f2b(v.z); h.w = f2b(v.w);
    *(ushort4a*)&tile[lk][tx * 4] = h;
  }
  __syncthreads();
#pragma unroll
  for (int i = 0; i < 4; ++i) {
    int ln = ty + i * 16;
    ushort4 v;
    v.x = tile[tx * 4 + 0][ln];
    v.y = tile[tx * 4 + 1][ln];
    v.z = tile[tx * 4 + 2][ln];
    v.w = tile[tx * 4 + 3][ln];
    *(ushort4a*)(T + (nb + ln) * 1024 + kb + tx * 4) = v;
  }
}

// ---------------------------------------------------------------------------
// GEMM: C[M][N] = A[M,1024] * Bt[N,1024]^T + bias[n]   (m97 structure)
// ---------------------------------------------------------------------------
__global__ __launch_bounds__(256) void gemm_bt(
    const u16* __restrict__ A,
    const u16* __restrict__ B0, const u16* __restrict__ B1, const u16* __restrict__ B2,
    const float* __restrict__ c0, const float* __restrict__ c1, const float* __restrict__ c2,
    u16* __restrict__ O0, u16* __restrict__ O1, u16* __restrict__ O2,
    float* __restrict__ Of, int plain) {
  __shared__ __align__(16) u16 sm[8192];
  u16* As = sm;
  u16* Bs = sm + 4096;
  const int tid = threadIdx.x, lane = tid & 63, w = tid >> 6;
  const int wm = w >> 1, wn = w & 1, quad = lane >> 4, l16 = lane & 15;
  const int z = blockIdx.z;
  const u16* Bt = z == 0 ? B0 : (z == 1 ? B1 : B2);
  const float* bi = z == 0 ? c0 : (z == 1 ? c1 : c2);
  u16* O = z == 0 ? O0 : (z == 1 ? O1 : O2);
  const int row0 = blockIdx.y * 128, col0 = blockIdx.x * 128;

  f32x4 acc[4][4];
#pragma unroll
  for (int i = 0; i < 4; ++i)
#pragma unroll
    for (int j = 0; j < 4; ++j) acc[i][j] = f32x4{0.f, 0.f, 0.f, 0.f};

  const int e0 = tid, e1 = tid + 256;
  const int r0 = e0 >> 2, cc0 = (e0 & 3) * 8;
  const int r1 = e1 >> 2, cc1 = (e1 & 3) * 8;
  const u32 lb0 = (u32)(w * 64) * 16;
  const u32 lb1 = (u32)(w * 64 + 256) * 16;

  for (int k0 = 0; k0 < 1024; k0 += 32) {
    __syncthreads();
    async16(A + (row0 + r0) * 1024 + k0 + cc0, (char*)As + lb0);
    async16(A + (row0 + r1) * 1024 + k0 + cc1, (char*)As + lb1);
    async16(Bt + (col0 + r0) * 1024 + k0 + cc0, (char*)Bs + lb0);
    async16(Bt + (col0 + r1) * 1024 + k0 + cc1, (char*)Bs + lb1);
    __syncthreads();
    bf8a af[4], bfr[4];
#pragma unroll
    for (int i = 0; i < 4; ++i) {
      af[i] = *(const bf8a*)(As + (wm * 64 + i * 16 + l16) * 32 + quad * 8);
      bfr[i] = *(const bf8a*)(Bs + (wn * 64 + i * 16 + l16) * 32 + quad * 8);
    }
#pragma unroll
    for (int mt = 0; mt < 4; ++mt)
#pragma unroll
      for (int nt = 0; nt < 4; ++nt) acc[mt][nt] = MFMA_BF16(af[mt], bfr[nt], acc[mt][nt]);
  }

#pragma unroll
  for (int nt = 0; nt < 4; ++nt) {
    const int col = col0 + wn * 64 + nt * 16 + l16;
    const float bcol = bi[col];
#pragma unroll
    for (int mt = 0; mt < 4; ++mt) {
#pragma unroll
      for (int r = 0; r < 4; ++r) {
        const int rm = row0 + wm * 64 + mt * 16 + quad * 4 + r;
        const float fv = acc[mt][nt][r] + bcol;
        if (plain) {
          Of[rm * 1024 + col] = fv;
        } else {
          const u16 hv = f2b(fv);
          const int s = rm >> 1, b_ = rm & 1, hh = col >> 6, e = col & 63;
          const int p = b_ * 16 + hh;
          if (z < 2) O[(p * 2048 + s) * 64 + e] = hv;  // [pair][s][64]
          else O[(p * 64 + e) * 2048 + s] = hv;        // [pair][e][s] (V^T)
        }
      }
    }
  }
}

// ---------------------------------------------------------------------------
// Flash attention v14: TLP-first restructure.
// v13 post-mortem: occupancy 20% (VGPR 116 + ~64 AGPR oacc = ~180 combined
// -> 2 waves/SIMD; LDS 51.7KB -> 3 blocks) was the binding constraint --
// per-SIMD slot 3675cy vs 2x1300cy issue = 29% idle minimum.
// v14: back to QBLK=32 (compact regs) and K LOADED DIRECTLY TO REGISTERS
// (v8's coalesced fragment pattern; K is L2-resident after XCD pinning, the
// LDS staging bought nothing and forced cross-wave barrier coupling).
//  - kf register double-buffer, eb register double-buffer, V JIT
//  - prefetches held live across the per-phase __syncthreads (the fence
//    that provably sticks: v12/v13); S-MFMA starts instantly at phase top
//  - LDS = P tiles only (17.2 KB); nominal regs ~126 combined -> 3-4
//    waves/SIMD; __launch_bounds__(256,3)
//  - XCD pinning kept: grid 2048 = 8 xcd * 4 pair * 64 qt
// ---------------------------------------------------------------------------
#define LOAD_K(kf, kt_)                                                             \
  {                                                                                 \
    const int tb_ = (kt_) * 128 + w * 32;                                           \
    _Pragma("unroll") for (int tt = 0; tt < 2; ++tt) {                              \
      const u16* kr_ = Kp + (tb_ + tt * 16 + l16) * 64 + quad * 8;                  \
      kf[tt][0] = *(const bf8a*)kr_;                                                \
      kf[tt][1] = *(const bf8a*)(kr_ + 32);                                         \
    }                                                                               \
  }

#define LOAD_E(eb, kt_)                                                             \
  {                                                                                 \
    const int tb16_ = (kt_) * 8 + w * 2;                                            \
    _Pragma("unroll") for (int st = 0; st < 2; ++st)                                \
      _Pragma("unroll") for (int tt = 0; tt < 2; ++tt)                              \
        eb[st][tt] = *(const uint2a*)(EBp + ((qt * 2 + st) * 128 + tb16_ + tt) * 256 \
                                      + l16 * 16 + quad * 4);                       \
  }

#define COMPUTE(kf, eb, kt_)                                                        \
  {                                                                                 \
    const int tb_ = (kt_) * 128 + w * 32;                                           \
    bf8a vf[4]; /* V^T JIT: rows e, k = t strip; consumed at PV (end) */            \
    _Pragma("unroll") for (int nt = 0; nt < 4; ++nt)                                \
      vf[nt] = *(const bf8a*)(Vp + (nt * 16 + l16) * 2048 + tb_ + quad * 8);        \
    f32x4 sacc[2][2]; /* [tt][st] */                                                \
    __builtin_amdgcn_s_setprio(1);                                                  \
    _Pragma("unroll") for (int tt = 0; tt < 2; ++tt)                                \
      _Pragma("unroll") for (int st = 0; st < 2; ++st) {                            \
        f32x4 t0_ = f32x4{0.f, 0.f, 0.f, 0.f};                                      \
        t0_ = MFMA_BF16(kf[tt][0], qf[st][0], t0_);                                 \
        sacc[tt][st] = MFMA_BF16(kf[tt][1], qf[st][1], t0_);                        \
      }                                                                             \
    __builtin_amdgcn_s_setprio(0);                                                  \
    _Pragma("unroll") for (int st = 0; st < 2; ++st) {                              \
      _Pragma("unroll") for (int tt = 0; tt < 2; ++tt) {                            \
        const uint2 e_ = eb[st][tt];                                                \
        const float g0 = __uint_as_float(e_.x << 16);                               \
        const float g1 = __uint_as_float(e_.x & 0xffff0000u);                       \
        const float g2 = __uint_as_float(e_.y << 16);                               \
        const float g3 = __uint_as_float(e_.y & 0xffff0000u);                       \
        const float p0 = __builtin_amdgcn_exp2f(sacc[tt][st][0] * c1) * g0;         \
        const float p1 = __builtin_amdgcn_exp2f(sacc[tt][st][1] * c1) * g1;         \
        const float p2 = __builtin_amdgcn_exp2f(sacc[tt][st][2] * c1) * g2;         \
        const float p3 = __builtin_amdgcn_exp2f(sacc[tt][st][3] * c1) * g3;         \
        lsum[st] += (__builtin_fabsf(p0) + __builtin_fabsf(p1)) +                   \
                    (__builtin_fabsf(p2) + __builtin_fabsf(p3));                    \
        uint2 v_;                                                                   \
        v_.x = pack2(p0, p1);                                                       \
        v_.y = pack2(p2, p3);                                                       \
        *(uint2a*)(Pw + st * 1152 + l16 * 72 + tt * 32 + quad * 8) = v_;            \
      }                                                                             \
    }                                                                               \
    _Pragma("unroll") for (int st = 0; st < 2; ++st) {                              \
      bf8a pf = *(const bf8a*)(Pw + st * 1152 + l16 * 72 + quad * 16);              \
      __builtin_amdgcn_s_setprio(1);                                                \
      _Pragma("unroll") for (int nt = 0; nt < 4; ++nt)                              \
        oacc[st][nt] = MFMA_BF16(vf[nt], pf, oacc[st][nt]);                         \
      __builtin_amdgcn_s_setprio(0);                                                \
    }                                                                               \
  }

__global__ __launch_bounds__(256, 3) void attn_fused(
    const u16* __restrict__ Qw, const u16* __restrict__ Kw, const u16* __restrict__ Vw,
    const u16* __restrict__ EBp, u16* __restrict__ Ao) {
  // LDS map: [0,9216) per-wave P tiles [4][2304 B]; epilogue Obuf
  // float[4][16][66] (16896 B) aliases [0,16896); [16896,17152) Lbuf [4][16].
  __shared__ __align__(16) char smem[17152];
  const int tid = threadIdx.x, lane = tid & 63, w = tid >> 6;
  const int quad = lane >> 4, l16 = lane & 15;
  const int id = blockIdx.x;
  const int xcd = id & 7, idx = id >> 3;
  const int pair = xcd * 4 + (idx & 3);  // pair fast: 4 pairs pinned per XCD
  const int qt = idx >> 2;               // qt slow (0..63): 32 q-rows per block
  const int bb = pair >> 4, hh = pair & 15;
  const u16* Qp = Qw + pair * (2048 * 64);
  const u16* Kp = Kw + pair * (2048 * 64);
  const u16* Vp = Vw + pair * (64 * 2048);
  const int s0 = qt * 32;  // block's 32 q-rows (shared by all waves)
  char* const Pw = smem + w * 2304;  // [2 st][16 s][36 t] u16 (pad 36)

  bf8a qf[2][2];  // B-operand (Q^T): [st][ks]; n=s, k=d
#pragma unroll
  for (int st = 0; st < 2; ++st)
#pragma unroll
    for (int ks = 0; ks < 2; ++ks)
      qf[st][ks] = *(const bf8a*)(Qp + (s0 + st * 16 + l16) * 64 + ks * 32 + quad * 8);

  f32x4 oacc[2][4];  // O^T partial: [st][nt]; e = nt*16+quad*4+r, s = st*16+l16
#pragma unroll
  for (int i = 0; i < 2; ++i)
#pragma unroll
    for (int j = 0; j < 4; ++j) oacc[i][j] = f32x4{0.f, 0.f, 0.f, 0.f};
  float lsum[2] = {0.f, 0.f};  // per-lane partial row-sum of |p|
  const float c1 = 0.125f * 1.44269504088896340736f;  // scale * log2(e)

  bf8a kfA[2][2], kfB[2][2];
  uint2 ebA[2][2], ebB[2][2];

  // prologue: K/EB(0) into A-regs
  LOAD_K(kfA, 0)
  LOAD_E(ebA, 0)

  for (int kt = 0; kt < 16; kt += 2) {
    // phase A: prefetch kt+1 into B-regs, compute kt from A-regs
    LOAD_K(kfB, kt + 1)
    LOAD_E(ebB, kt + 1)
    COMPUTE(kfA, ebA, kt)
    __syncthreads();  // fence: B-prefetch cannot sink past here
    // phase B: prefetch kt+2 into A-regs, compute kt+1 from B-regs
    if (kt < 14) {
      LOAD_K(kfA, kt + 2)
      LOAD_E(ebA, kt + 2)
    }
    COMPUTE(kfB, ebB, kt + 1)
    __syncthreads();  // fence: A-prefetch cannot sink past here
  }

  // ---------------- merge epilogue (plain sums, 2 st-passes) ----------------
  // last loop barrier guarantees all waves done with P before Obuf aliasing
  float* const Obuf = (float*)smem;             // [4][16 s][66 e]
  float* const Lbuf = (float*)(smem + 16896);   // [4][16 s]
#pragma unroll
  for (int st = 0; st < 2; ++st) {
    float ls = lsum[st];
    ls += __shfl_xor(ls, 16);
    ls += __shfl_xor(ls, 32);
    if (lane < 16) Lbuf[w * 16 + l16] = ls;
#pragma unroll
    for (int nt = 0; nt < 4; ++nt)
      *(float4a*)&Obuf[w * 1056 + l16 * 66 + nt * 16 + quad * 4] = (float4){
          oacc[st][nt][0], oacc[st][nt][1], oacc[st][nt][2], oacc[st][nt][3]};
    __syncthreads();
    // sum across waves + write: s = tid&15, e = (tid>>4)*4 + [0,4)
    {
      const int s_ = tid & 15, eg = (tid >> 4) * 4;
      float a0 = 0.f, a1 = 0.f, a2 = 0.f, a3 = 0.f;
#pragma unroll
      for (int wp = 0; wp < 4; ++wp) {
        const float4 x = *(const float4a*)&Obuf[wp * 1056 + s_ * 66 + eg];
        a0 += x.x; a1 += x.y; a2 += x.z; a3 += x.w;
      }
      const float lt = Lbuf[s_] + Lbuf[16 + s_] + Lbuf[32 + s_] + Lbuf[48 + s_];
      const float inv = 1.0f / lt;
      ushort4 o;
      o.x = f2b(a0 * inv); o.y = f2b(a1 * inv); o.z = f2b(a2 * inv); o.w = f2b(a3 * inv);
      *(ushort4a*)(Ao + ((s0 + st * 16 + s_) * 2 + bb) * 1024 + hh * 64 + eg) = o;
    }
    if (st == 0) __syncthreads();  // before pass 1 overwrites Obuf/Lbuf
  }
}

// ---------------------------------------------------------------------------
extern "C" void kernel_launch(void* const* d_in, const int* in_sizes, int n_in,
                              void* d_out, int out_size, void* d_ws, size_t ws_size,
                              hipStream_t stream) {
  const float* src = (const float*)d_in[0];
  const float* eb = (const float*)d_in[1];
  const float* wq = (const float*)d_in[2];
  const float* bq = (const float*)d_in[3];
  const float* wk = (const float*)d_in[4];
  const float* bk = (const float*)d_in[5];
  const float* wv = (const float*)d_in[6];
  const float* bv = (const float*)d_in[7];
  const float* wo = (const float*)d_in[8];
  const float* bo = (const float*)d_in[9];
  u16* ws = (u16*)d_ws;
  const size_t MM = 1024 * 1024;
  u16* wqT = ws;             // bf16 [N][K]
  u16* wkT = ws + MM;
  u16* wvT = ws + 2 * MM;
  u16* woT = ws + 3 * MM;
  u16* srcB = ws + 4 * MM;   // bf16 [4096][1024] -- dead after QKV GEMM
  u16* eb2 = ws + 4 * MM;    // bf16 tiled signed-exp EB (aliases srcB, written after)
  u16* qW = ws + 8 * MM;     // bf16 [32][2048][64]
  u16* kW = ws + 12 * MM;    // bf16 [32][2048][64]
  u16* vW = ws + 16 * MM;    // bf16 [32][64][2048] (V^T)
  u16* aO = ws + 20 * MM;    // bf16 [4096][1024]
  float* out = (float*)d_out;

  convert_src<<<dim3(4096), 256, 0, stream>>>(src, srcB);
  transpose4<<<dim3(16, 16, 4), 256, 0, stream>>>(wq, wk, wv, wo, wqT, wkT, wvT, woT);
  gemm_bt<<<dim3(8, 32, 3), 256, 0, stream>>>(srcB, wqT, wkT, wvT, bq, bk, bv,
                                              qW, kW, vW, nullptr, 0);
  prep_eb<<<dim3(4096), 256, 0, stream>>>(eb, eb2);  // after QKV GEMM (aliases srcB)
  attn_fused<<<dim3(2048), 256, 0, stream>>>(qW, kW, vW, eb2, aO);
  gemm_bt<<<dim3(8, 32, 1), 256, 0, stream>>>(aO, woT, woT, woT, bo, bo, bo,
                                              nullptr, nullptr, nullptr, out, 1);
}